// Round 9
// baseline (92.710 us; speedup 1.0000x reference)
//
#include <hip/hip_runtime.h>
#include <math.h>

#define NV 1000000
#define NC 4000000
#define NGROUP (NC / 4)    // 1,000,000 groups of 4 clauses
#define G2 (NGROUP / 2)    // 500,000 threads, two groups each
#define TPB 256

typedef int   vint4   __attribute__((ext_vector_type(4)));
typedef float vfloat4 __attribute__((ext_vector_type(4)));

__device__ __forceinline__ float sigf(float x) { return 1.0f / (1.0f + __expf(-x)); }

// Kernel A: 1-thread scalar seed (separate dispatch => ordered before kernel B's atomics)
__global__ void sat_seed(float* __restrict__ sc) {
    sc[0] = INFINITY;   // all_satisfied (min)
    sc[1] = 0.0f;       // n_satisfied  (sum)
}

// literal value = sigmoid(sign ? x : -x) == sign ? sigmoid(x) : 1-sigmoid(x)
__device__ __forceinline__ float litv(float x, int s) { return sigf(s ? x : -x); }

// Kernel B: fused assignments + clauses. Direct f32 logit gathers (no table,
// no prologue dependency); 24 independent divergent gathers in flight.
__global__ __launch_bounds__(TPB) void sat_fused(
    const float* __restrict__ logits,
    const vint4* __restrict__ vars4,
    const vint4* __restrict__ signs4,
    float* __restrict__ out)           // [0,NV) assignments | [NV,NV+NC) sats | 2 scalars
{
    const int g = blockIdx.x * TPB + threadIdx.x;
    float minv = INFINITY;
    float fcnt = 0.0f;

    // Part A: assignments = sigmoid(logits), f32 exact, coalesced
    if (g < NV / 4) {
        vfloat4 v = ((const vfloat4*)logits)[g];
        vfloat4 r;
        r.x = sigf(v.x); r.y = sigf(v.y); r.z = sigf(v.z); r.w = sigf(v.w);
        ((vfloat4*)out)[g] = r;
    }

    // Part B: 2 clause-groups per thread (8 clauses, 24 gathers)
    if (g < G2) {
        const int h = g + G2;
        // 6 coalesced var-index loads (gathers depend on these)
        vint4 a0 = vars4[3 * g], a1 = vars4[3 * g + 1], a2 = vars4[3 * g + 2];
        vint4 b0 = vars4[3 * h], b1 = vars4[3 * h + 1], b2 = vars4[3 * h + 2];

        // 24 independent divergent gathers, all issued before any use
        float u0  = logits[a0.x], u1  = logits[a0.y], u2  = logits[a0.z];
        float u3  = logits[a0.w], u4  = logits[a1.x], u5  = logits[a1.y];
        float u6  = logits[a1.z], u7  = logits[a1.w], u8  = logits[a2.x];
        float u9  = logits[a2.y], u10 = logits[a2.z], u11 = logits[a2.w];
        float w0  = logits[b0.x], w1  = logits[b0.y], w2  = logits[b0.z];
        float w3  = logits[b0.w], w4  = logits[b1.x], w5  = logits[b1.y];
        float w6  = logits[b1.z], w7  = logits[b1.w], w8  = logits[b2.x];
        float w9  = logits[b2.y], w10 = logits[b2.z], w11 = logits[b2.w];

        // sign loads overlap gather latency
        vint4 sa0 = signs4[3 * g], sa1 = signs4[3 * g + 1], sa2 = signs4[3 * g + 2];
        vint4 sb0 = signs4[3 * h], sb1 = signs4[3 * h + 1], sb2 = signs4[3 * h + 2];

        vfloat4 r, q;
        r.x = fmaxf(fmaxf(litv(u0, sa0.x), litv(u1,  sa0.y)), litv(u2,  sa0.z));
        r.y = fmaxf(fmaxf(litv(u3, sa0.w), litv(u4,  sa1.x)), litv(u5,  sa1.y));
        r.z = fmaxf(fmaxf(litv(u6, sa1.z), litv(u7,  sa1.w)), litv(u8,  sa2.x));
        r.w = fmaxf(fmaxf(litv(u9, sa2.y), litv(u10, sa2.z)), litv(u11, sa2.w));
        q.x = fmaxf(fmaxf(litv(w0, sb0.x), litv(w1,  sb0.y)), litv(w2,  sb0.z));
        q.y = fmaxf(fmaxf(litv(w3, sb0.w), litv(w4,  sb1.x)), litv(w5,  sb1.y));
        q.z = fmaxf(fmaxf(litv(w6, sb1.z), litv(w7,  sb1.w)), litv(w8,  sb2.x));
        q.w = fmaxf(fmaxf(litv(w9, sb2.y), litv(w10, sb2.z)), litv(w11, sb2.w));

        __builtin_nontemporal_store(r, (vfloat4*)(out + NV) + g);
        __builtin_nontemporal_store(q, (vfloat4*)(out + NV) + h);

        minv = fminf(fminf(fminf(r.x, r.y), fminf(r.z, r.w)),
                     fminf(fminf(q.x, q.y), fminf(q.z, q.w)));
        fcnt = (float)((r.x > 0.5f) + (r.y > 0.5f) + (r.z > 0.5f) + (r.w > 0.5f) +
                       (q.x > 0.5f) + (q.y > 0.5f) + (q.z > 0.5f) + (q.w > 0.5f));
    }

    // wave + block reduction (idle threads hold INF/0)
    #pragma unroll
    for (int off = 32; off > 0; off >>= 1) {
        minv = fminf(minv, __shfl_down(minv, off));
        fcnt += __shfl_down(fcnt, off);
    }
    __shared__ float smin[TPB / 64];
    __shared__ float scnt[TPB / 64];
    const int wave = threadIdx.x >> 6, lane = threadIdx.x & 63;
    if (lane == 0) { smin[wave] = minv; scnt[wave] = fcnt; }
    __syncthreads();
    if (threadIdx.x == 0) {
        float m = smin[0], s = scnt[0];
        #pragma unroll
        for (int w = 1; w < TPB / 64; ++w) { m = fminf(m, smin[w]); s += scnt[w]; }
        // all satisfaction values are > 0 → uint ordering == float ordering
        atomicMin((unsigned int*)(out + NV + NC), __float_as_uint(m));
        atomicAdd(out + NV + NC + 1, s);   // integer-valued: exact, order-independent
    }
}

extern "C" void kernel_launch(void* const* d_in, const int* in_sizes, int n_in,
                              void* d_out, int out_size, void* d_ws, size_t ws_size,
                              hipStream_t stream) {
    const float* logits = (const float*)d_in[0];
    const vint4* vars4  = (const vint4*)d_in[1];
    const vint4* signs4 = (const vint4*)d_in[2];
    float* out = (float*)d_out;

    sat_seed<<<1, 1, 0, stream>>>(out + NV + NC);

    const int blkB = (G2 + TPB - 1) / TPB;
    sat_fused<<<blkB, TPB, 0, stream>>>(logits, vars4, signs4, out);
}

// Round 10
// 73.319 us; speedup vs baseline: 1.2645x; 1.2645x over previous
//
#include <hip/hip_runtime.h>
#include <math.h>

#define NV 1000000
#define NC 4000000
#define NGROUP (NC / 4)    // 1,000,000 groups of 4 clauses
#define G2 (NGROUP / 2)    // 500,000 threads, two groups each
#define TPB 1024           // clauses kernel block size
#define TPB_A 256          // table-build block size

typedef _Float16 half_t;
typedef _Float16 half4_t __attribute__((ext_vector_type(4)));
typedef int   vint4   __attribute__((ext_vector_type(4)));
typedef float vfloat4 __attribute__((ext_vector_type(4)));

__device__ __forceinline__ float sigf(float x) { return 1.0f / (1.0f + __expf(-x)); }

// Kernel A: fp16 sigmoid gather-table + scalar seeds (~2.5 us prologue).
// 2 MB fp16 table is the key: it co-resides in each XCD's 4 MB L2 with the
// streaming index data (4 MB f32 table does NOT — R9: +26% dur, 3x FETCH).
__global__ __launch_bounds__(TPB_A) void tbl_build(
    const float* __restrict__ logits,
    half_t* __restrict__ tbl,
    float* __restrict__ out)
{
    const int i = blockIdx.x * TPB_A + threadIdx.x;
    if (i == 0) {  // seed reduction scalars (d_out is never re-poisoned between replays)
        out[NV + NC]     = INFINITY;
        out[NV + NC + 1] = 0.0f;
    }
    if (i < NV / 4) {
        vfloat4 v = ((const vfloat4*)logits)[i];
        half4_t h;
        h.x = (half_t)sigf(v.x); h.y = (half_t)sigf(v.y);
        h.z = (half_t)sigf(v.z); h.w = (half_t)sigf(v.w);
        ((half4_t*)tbl)[i] = h;
    }
}

__device__ __forceinline__ float litv(float sg, int s) { return s ? sg : 1.0f - sg; }

// Kernel B: clauses (2 groups/thread, 24 divergent gathers in flight)
// + folded assignments output (coalesced traffic rides free under gather latency).
// Plain (cached) index loads: NT variants measured slower (R8).
__global__ __launch_bounds__(TPB) void sat_clauses(
    const float*  __restrict__ logits,
    const half_t* __restrict__ tbl,
    const vint4*  __restrict__ vars4,
    const vint4*  __restrict__ signs4,
    float* __restrict__ out)
{
    const int g = blockIdx.x * TPB + threadIdx.x;
    float minv = INFINITY;
    float fcnt = 0.0f;

    // folded Part A: assignments = sigmoid(logits), f32, exact
    if (g < NV / 4) {
        vfloat4 v = ((const vfloat4*)logits)[g];
        vfloat4 r;
        r.x = sigf(v.x); r.y = sigf(v.y); r.z = sigf(v.z); r.w = sigf(v.w);
        ((vfloat4*)out)[g] = r;
    }

    if (g < G2) {
        const int h = g + G2;
        // 6 coalesced var-index loads (gathers depend on these)
        vint4 a0 = vars4[3 * g], a1 = vars4[3 * g + 1], a2 = vars4[3 * g + 2];
        vint4 b0 = vars4[3 * h], b1 = vars4[3 * h + 1], b2 = vars4[3 * h + 2];

        // 24 independent divergent gathers, all issued before any use
        float u0  = (float)tbl[a0.x], u1  = (float)tbl[a0.y], u2  = (float)tbl[a0.z];
        float u3  = (float)tbl[a0.w], u4  = (float)tbl[a1.x], u5  = (float)tbl[a1.y];
        float u6  = (float)tbl[a1.z], u7  = (float)tbl[a1.w], u8  = (float)tbl[a2.x];
        float u9  = (float)tbl[a2.y], u10 = (float)tbl[a2.z], u11 = (float)tbl[a2.w];
        float w0  = (float)tbl[b0.x], w1  = (float)tbl[b0.y], w2  = (float)tbl[b0.z];
        float w3  = (float)tbl[b0.w], w4  = (float)tbl[b1.x], w5  = (float)tbl[b1.y];
        float w6  = (float)tbl[b1.z], w7  = (float)tbl[b1.w], w8  = (float)tbl[b2.x];
        float w9  = (float)tbl[b2.y], w10 = (float)tbl[b2.z], w11 = (float)tbl[b2.w];

        // sign loads overlap gather latency
        vint4 sa0 = signs4[3 * g], sa1 = signs4[3 * g + 1], sa2 = signs4[3 * g + 2];
        vint4 sb0 = signs4[3 * h], sb1 = signs4[3 * h + 1], sb2 = signs4[3 * h + 2];

        vfloat4 r, q;
        r.x = fmaxf(fmaxf(litv(u0, sa0.x), litv(u1,  sa0.y)), litv(u2,  sa0.z));
        r.y = fmaxf(fmaxf(litv(u3, sa0.w), litv(u4,  sa1.x)), litv(u5,  sa1.y));
        r.z = fmaxf(fmaxf(litv(u6, sa1.z), litv(u7,  sa1.w)), litv(u8,  sa2.x));
        r.w = fmaxf(fmaxf(litv(u9, sa2.y), litv(u10, sa2.z)), litv(u11, sa2.w));
        q.x = fmaxf(fmaxf(litv(w0, sb0.x), litv(w1,  sb0.y)), litv(w2,  sb0.z));
        q.y = fmaxf(fmaxf(litv(w3, sb0.w), litv(w4,  sb1.x)), litv(w5,  sb1.y));
        q.z = fmaxf(fmaxf(litv(w6, sb1.z), litv(w7,  sb1.w)), litv(w8,  sb2.x));
        q.w = fmaxf(fmaxf(litv(w9, sb2.y), litv(w10, sb2.z)), litv(w11, sb2.w));

        __builtin_nontemporal_store(r, (vfloat4*)(out + NV) + g);
        __builtin_nontemporal_store(q, (vfloat4*)(out + NV) + h);

        minv = fminf(fminf(fminf(r.x, r.y), fminf(r.z, r.w)),
                     fminf(fminf(q.x, q.y), fminf(q.z, q.w)));
        fcnt = (float)((r.x > 0.5f) + (r.y > 0.5f) + (r.z > 0.5f) + (r.w > 0.5f) +
                       (q.x > 0.5f) + (q.y > 0.5f) + (q.z > 0.5f) + (q.w > 0.5f));
    }

    // wave + block reduction (idle threads hold INF/0)
    #pragma unroll
    for (int off = 32; off > 0; off >>= 1) {
        minv = fminf(minv, __shfl_down(minv, off));
        fcnt += __shfl_down(fcnt, off);
    }
    __shared__ float smin[TPB / 64];
    __shared__ float scnt[TPB / 64];
    const int wave = threadIdx.x >> 6, lane = threadIdx.x & 63;
    if (lane == 0) { smin[wave] = minv; scnt[wave] = fcnt; }
    __syncthreads();
    if (threadIdx.x == 0) {
        float m = smin[0], s = scnt[0];
        #pragma unroll
        for (int w = 1; w < TPB / 64; ++w) { m = fminf(m, smin[w]); s += scnt[w]; }
        // all satisfaction values are > 0 → uint ordering == float ordering
        atomicMin((unsigned int*)(out + NV + NC), __float_as_uint(m));
        atomicAdd(out + NV + NC + 1, s);   // integer-valued: exact, order-independent
    }
}

extern "C" void kernel_launch(void* const* d_in, const int* in_sizes, int n_in,
                              void* d_out, int out_size, void* d_ws, size_t ws_size,
                              hipStream_t stream) {
    const float* logits = (const float*)d_in[0];
    const vint4* vars4  = (const vint4*)d_in[1];
    const vint4* signs4 = (const vint4*)d_in[2];
    float* out = (float*)d_out;
    half_t* tbl = (half_t*)d_ws;   // 2 MB, ws_size is ample

    const int blkA = (NV / 4 + TPB_A - 1) / TPB_A;
    tbl_build<<<blkA, TPB_A, 0, stream>>>(logits, tbl, out);

    const int blkB = (G2 + TPB - 1) / TPB;
    sat_clauses<<<blkB, TPB, 0, stream>>>(logits, tbl, vars4, signs4, out);
}